// Round 17
// baseline (217.517 us; speedup 1.0000x reference)
//
#include <hip/hip_runtime.h>

// LDPC BP decoder, (3,6)-regular — fused full-chip version, table-phi v2.
// Edge e (vn order) = 3v+j; c = e mod 8192, t = e div 8192, e = c + 8192t.
//
// r16 -> r17 (no FP change; absmax must stay exactly 0.25):
//  (a) log table as double2 -> one ds_read_b128 per log (was 2 dependent b64)
//  (b) gather/compute split in cn_fused: all 24 global loads issued before
//      the 12 phi chains -> L2 latency overlaps itself, phis run from regs.

constexpr int NUM_VNS   = 16384;
constexpr int NUM_CNS   = 8192;
constexpr int NUM_EDGES = 49152;
constexpr int BATCH     = 128;
constexpr int NUM_ITER  = 8;
constexpr float LLR_MAX = 20.0f;
constexpr float PHI_MIN = 8.5e-8f;
constexpr float PHI_MAX = 16.635532f;

// ---- full-accuracy reference primitives (table init + fallback path) ----
__device__ __forceinline__ double lean_exp(double x) {
    double t = x * 1.4426950408889634;
    double k = __builtin_rint(t);
    double r = __builtin_fma(-k, 0.6931471805599453, x);
    r = __builtin_fma(-k, 2.3190468138462996e-17, r);
    double p = 1.0 / 3628800.0;                  // Taylor deg 10, |r|<=0.347
    p = __builtin_fma(p, r, 1.0 / 362880.0);
    p = __builtin_fma(p, r, 1.0 / 40320.0);
    p = __builtin_fma(p, r, 1.0 / 5040.0);
    p = __builtin_fma(p, r, 1.0 / 720.0);
    p = __builtin_fma(p, r, 1.0 / 120.0);
    p = __builtin_fma(p, r, 1.0 / 24.0);
    p = __builtin_fma(p, r, 1.0 / 6.0);
    p = __builtin_fma(p, r, 0.5);
    p = __builtin_fma(p, r, 1.0);
    p = __builtin_fma(p, r, 1.0);
    int ik = (int)k;                              // k in [0,24]
    double s = __hiloint2double((1023 + ik) << 20, 0);
    return p * s;
}

__device__ __forceinline__ double lean_log(double v) {
    int hv = __double2hiint(v);
    int lv = __double2loint(v);
    int e  = (hv >> 20) - 1023;
    double m = __hiloint2double((hv & 0x000FFFFF) | 0x3FF00000, lv);
    if (m >= 1.4142135623730951) { m *= 0.5; e += 1; }   // m in [0.7071,1.4142)
    double t = m - 1.0;
    double d = t + 2.0;
    double r = (double)__builtin_amdgcn_rcpf((float)d);
    r = __builtin_fma(__builtin_fma(-d, r, 1.0), r, r);
    double u = t * r;
    double w = u * u;
    double P = 2.0 / 13.0;                        // 2*artanh: deg 6 in w
    P = __builtin_fma(P, w, 2.0 / 11.0);
    P = __builtin_fma(P, w, 2.0 / 9.0);
    P = __builtin_fma(P, w, 2.0 / 7.0);
    P = __builtin_fma(P, w, 2.0 / 5.0);
    P = __builtin_fma(P, w, 2.0 / 3.0);
    P = __builtin_fma(P, w, 2.0);
    double lm = u * P;
    return __builtin_fma((double)e, 0.6931471805599453, lm);
}

__device__ __forceinline__ float phi_f(float xf) {
    xf = fminf(fmaxf(xf, PHI_MIN), PHI_MAX);
    float exf = (float)lean_exp((double)xf);
    float af = exf + 1.0f;
    float bf = exf - 1.0f;
    float la = (float)lean_log((double)af);
    float lb = (float)lean_log((double)bf);
    return la - lb;
}

// ---- fast table primitives (main path) ----
constexpr double EXP_STEP = 0.021660849392498291;   // double(ln2/32)
constexpr double EXP_INV  = 46.166241308446828;     // 32/ln2

// e^x, x in [0, 16.64]; rel err <= r^4/24 ~ 2^-30.7, and -> 0 as x -> 0.
__device__ __forceinline__ double fast_exp(double x, const double* et) {
    double kd = __builtin_rint(x * EXP_INV);
    double r  = __builtin_fma(-kd, EXP_STEP, x);     // |r| <= 0.01083
    int n = (int)kd;                                 // [0, 768]
    double p = __builtin_fma(
        r, __builtin_fma(r, __builtin_fma(r, 1.0 / 6.0, 0.5), 1.0), 1.0);
    double s = et[n & 31];                           // 2^(j/32)
    int sh = __double2hiint(s) + ((n >> 5) << 20);   // * 2^k
    s = __hiloint2double(sh, __double2loint(s));
    return p * s;
}

// log(v), v an exact f32 in [2^-23, 2^25]; abs err ~2^-32.3.
// Table entry = double2{1/t, log t}: single ds_read_b128.
__device__ __forceinline__ double fast_log(double v, const double2* lt) {
    int hv = __double2hiint(v);
    int lv = __double2loint(v);
    int E  = (hv >> 20) - 1023;
    double m = __hiloint2double((hv & 0x000FFFFF) | 0x3FF00000, lv); // [1,2)
    int idx = (hv >> 14) & 63;
    double2 te = lt[idx];                            // {1/t, log t}
    double t = __hiloint2double(0x3FF00000 | (idx << 14), 0);        // 1+idx/64
    double d = m - t;                                // exact (Sterbenz)
    double f = d * te.x;                             // d / t, f in [0, 2^-6)
    double P = __builtin_fma(f, __builtin_fma(f, -0.25, 1.0 / 3.0), -0.5);
    double q = __builtin_fma(f * f, P, f);           // log1p(f), deg 4
    return __builtin_fma((double)E, 0.6931471805599453, te.y + q);
}

// literal reference chain with table primitives (same f32 rounding points).
__device__ __forceinline__ float phi_fast(float xf, const double2* lt,
                                          const double* et) {
    xf = fminf(fmaxf(xf, PHI_MIN), PHI_MAX);
    float exf = (float)fast_exp((double)xf, et);
    float af = exf + 1.0f;
    float bf = exf - 1.0f;
    float la = (float)fast_log((double)af, lt);
    float lb = (float)fast_log((double)bf, lt);
    return la - lb;
}

// ---- fused CN kernel, XCD-sharded, gather/compute split. ----
template<int FIRST>
__global__ __launch_bounds__(256)
void cn_fused(const float* __restrict__ llr, const float* __restrict__ msgIn,
              float* __restrict__ msgOut)
{
    __shared__ double2 lt[64];   // {1/t, log t} per 64 mantissa bins
    __shared__ double  et[32];   // 2^(j/32)
    {
        int tid = threadIdx.x;
        if (tid < 64) {
            double t = 1.0 + tid * 0.015625;
            double r0 = (double)__builtin_amdgcn_rcpf((float)t);
            r0 = __builtin_fma(__builtin_fma(-t, r0, 1.0), r0, r0);
            r0 = __builtin_fma(__builtin_fma(-t, r0, 1.0), r0, r0);
            lt[tid] = make_double2(r0, lean_log(t));
        } else if (tid < 96) {
            int j = tid - 64;
            et[j] = lean_exp(j * EXP_STEP);
        }
    }
    __syncthreads();

    int bid = blockIdx.x;
    int seq = bid >> 3;                          // [0, 512)
    int b   = (bid & 7) * 16 + (seq >> 5);       // 16 batches per XCD
    int c   = (seq & 31) * 256 + threadIdx.x;    // [0, 8192)

    const float* mi = msgIn + (size_t)b * NUM_EDGES;
    float* mo = msgOut + (size_t)b * NUM_EDGES;
    const float* lbp = llr + (size_t)b * NUM_VNS;

    // ---- gather pass: issue ALL global loads before any phi math ----
    float xv[6];                                 // raw llr (clip deferred)
    float mm0[6], mm1[6], mm2[6];                // the 3 msgs of each edge's VN
    int   jj[6];                                 // e mod 3
#pragma unroll
    for (int t = 0; t < 6; ++t) {
        int e = c + (t << 13);
        int v = (int)(((unsigned)e * 43691u) >> 17);  // e/3, e < 98304
        xv[t] = lbp[v];
        if (!FIRST) {
            int e0 = 3 * v;
            jj[t]  = e - e0;
            mm0[t] = mi[e0];
            mm1[t] = mi[e0 + 1];
            mm2[t] = mi[e0 + 2];
        }
    }

    // ---- compute pass 1: signed mags (sign folded into bit) ----
    float g[6];
#pragma unroll
    for (int t = 0; t < 6; ++t) {
        float x = fminf(fmaxf(xv[t], -LLR_MAX), LLR_MAX);
        float m;
        if (FIRST) {
            m = -x;                                   // msgs are all zero
        } else {
            float s = ((mm0[t] + mm1[t]) + mm2[t]) - x;   // exact order
            float own = (jj[t] == 0) ? mm0[t] : ((jj[t] == 1) ? mm1[t] : mm2[t]);
            m = s - own;                              // vn-extrinsic
        }
        unsigned neg = (m < 0.0f) ? 0x80000000u : 0u; // sign(0) -> +1
        float mg = phi_fast(fabsf(m), lt, et);
        g[t] = __uint_as_float(__float_as_uint(mg) | neg);
    }
    float a0 = fabsf(g[0]), a1 = fabsf(g[1]), a2 = fabsf(g[2]);
    float a3 = fabsf(g[3]), a4 = fabsf(g[4]), a5 = fabsf(g[5]);
    float ms = ((((a0 + a1) + a2) + a3) + a4) + a5;   // reference left-fold
    unsigned all6 = (__float_as_uint(g[0]) ^ __float_as_uint(g[1])
                   ^ __float_as_uint(g[2]) ^ __float_as_uint(g[3])
                   ^ __float_as_uint(g[4]) ^ __float_as_uint(g[5]))
                  & 0x80000000u;
    // ---- compute pass 2: output messages ----
#pragma unroll
    for (int t = 0; t < 6; ++t) {
        int e = c + (t << 13);
        float o = phi_fast(ms - fabsf(g[t]), lt, et);
        unsigned sg = all6 ^ (__float_as_uint(g[t]) & 0x80000000u);
        mo[e] = __uint_as_float(__float_as_uint(o) ^ sg);
    }
}

// ---- final marginalize, XCD-sharded to match cn_fused's batch->XCD map. ----
__global__ __launch_bounds__(256)
void vn_final(const float* __restrict__ llr, const float* __restrict__ msg,
              float* __restrict__ outv)
{
    int bid = blockIdx.x;                        // 8192 blocks
    int seq = bid >> 3;                          // [0, 1024)
    int b   = (bid & 7) * 16 + (seq >> 6);       // 16 batches per XCD
    int v   = (seq & 63) * 256 + threadIdx.x;    // [0, 16384)
    float x = fminf(fmaxf(llr[(size_t)b * NUM_VNS + v], -LLR_MAX), LLR_MAX);
    const float* mb = msg + (size_t)b * NUM_EDGES;
    int e = 3 * v;
    float s = ((mb[e] + mb[e + 1]) + mb[e + 2]) - x;  // exact reference order
    outv[(size_t)b * NUM_VNS + v] = -s;
}

// ---- VN kernel (r12 fallback). ----
template<int FIRST, int LAST>
__global__ __launch_bounds__(256)
void vn_kernel(const float* __restrict__ llr, const float* __restrict__ msg,
               float* __restrict__ outv)
{
    int gid = blockIdx.x * 256 + threadIdx.x;       // b*16384 + v
    int b = gid >> 14;
    int v = gid & 16383;
    float x = fminf(fmaxf(llr[gid], -LLR_MAX), LLR_MAX);
    float s;
    if (FIRST) {
        s = -x;
    } else {
        const float* mb = msg + (size_t)b * NUM_EDGES;
        int e = 3 * v;
        s = ((mb[e] + mb[e + 1]) + mb[e + 2]) - x;
    }
    outv[gid] = LAST ? -s : s;
}

// ---- CN kernel (r12 fallback, reads precomputed vtot). ----
template<int FIRST>
__global__ __launch_bounds__(256)
void cn_kernel(float* __restrict__ msg, const float* __restrict__ vtot)
{
    int gid = blockIdx.x * 256 + threadIdx.x;       // b*8192 + c
    int b = gid >> 13;
    int c = gid & 8191;
    float* mb = msg + (size_t)b * NUM_EDGES;
    const float* vt = vtot + (size_t)b * NUM_VNS;

    float g[6];
#pragma unroll
    for (int t = 0; t < 6; ++t) {
        int e = c + (t << 13);
        int v = (int)(((unsigned)e * 43691u) >> 17);
        float m = FIRST ? vt[v] : (vt[v] - mb[e]);
        unsigned neg = (m < 0.0f) ? 0x80000000u : 0u;
        float mg = phi_f(fabsf(m));
        g[t] = __uint_as_float(__float_as_uint(mg) | neg);
    }
    float a0 = fabsf(g[0]), a1 = fabsf(g[1]), a2 = fabsf(g[2]);
    float a3 = fabsf(g[3]), a4 = fabsf(g[4]), a5 = fabsf(g[5]);
    float ms = ((((a0 + a1) + a2) + a3) + a4) + a5;
    unsigned all6 = (__float_as_uint(g[0]) ^ __float_as_uint(g[1])
                   ^ __float_as_uint(g[2]) ^ __float_as_uint(g[3])
                   ^ __float_as_uint(g[4]) ^ __float_as_uint(g[5]))
                  & 0x80000000u;
#pragma unroll
    for (int t = 0; t < 6; ++t) {
        int e = c + (t << 13);
        float o = phi_f(ms - fabsf(g[t]));
        unsigned sg = all6 ^ (__float_as_uint(g[t]) & 0x80000000u);
        mb[e] = __uint_as_float(__float_as_uint(o) ^ sg);
    }
}

extern "C" void kernel_launch(void* const* d_in, const int* in_sizes, int n_in,
                              void* d_out, int out_size, void* d_ws, size_t ws_size,
                              hipStream_t stream) {
    const float* llr = (const float*)d_in[0];
    float* out = (float*)d_out;

    const int VNB = BATCH * NUM_VNS / 256;             // 8192 blocks
    const int CNB = BATCH * NUM_CNS / 256;             // 4096 blocks
    const size_t MSGSZ = (size_t)BATCH * NUM_EDGES;    // 6.29M floats = 24 MB

    if (ws_size >= 2 * MSGSZ * sizeof(float)) {
        // ---- fused path: 8 CN launches (double-buffered) + final VN ----
        float* buf0 = (float*)d_ws;
        float* buf1 = buf0 + MSGSZ;
        cn_fused<1><<<CNB, 256, 0, stream>>>(llr, buf0, buf0);     // writes buf0
        for (int it = 1; it < NUM_ITER; ++it) {
            float* in  = (it & 1) ? buf0 : buf1;
            float* dst = (it & 1) ? buf1 : buf0;
            cn_fused<0><<<CNB, 256, 0, stream>>>(llr, in, dst);
        }
        // NUM_ITER=8: last write was buf1 (it=7 -> dst=buf1)
        vn_final<<<VNB, 256, 0, stream>>>(llr, buf1, out);
    } else {
        // ---- r12 fallback: 32 MB workspace ----
        float* msg  = (float*)d_ws;
        float* vtot = msg + MSGSZ;
        vn_kernel<1, 0><<<VNB, 256, 0, stream>>>(llr, msg, vtot);
        cn_kernel<1><<<CNB, 256, 0, stream>>>(msg, vtot);
        for (int it = 1; it < NUM_ITER; ++it) {
            vn_kernel<0, 0><<<VNB, 256, 0, stream>>>(llr, msg, vtot);
            cn_kernel<0><<<CNB, 256, 0, stream>>>(msg, vtot);
        }
        vn_kernel<0, 1><<<VNB, 256, 0, stream>>>(llr, msg, out);
    }
}

// Round 18
// 204.540 us; speedup vs baseline: 1.0634x; 1.0634x over previous
//
#include <hip/hip_runtime.h>

// LDPC BP decoder, (3,6)-regular — fused full-chip version, table-phi v3.
// Edge e (vn order) = 3v+j; c = e mod 8192, t = e div 8192, e = c + 8192t.
//
// r17 -> r18 (no semantic change; absmax must stay exactly 0.25):
//   log table 64 -> 256 entries (f <= 2^-8) => log1p poly deg-4 -> deg-3
//   (err f^4/4 ~ 2^-34, better than before, 1 fewer f64 FMA per log).
//   Body reverted to r16's interleaved form (r17's gather split was neutral).

constexpr int NUM_VNS   = 16384;
constexpr int NUM_CNS   = 8192;
constexpr int NUM_EDGES = 49152;
constexpr int BATCH     = 128;
constexpr int NUM_ITER  = 8;
constexpr float LLR_MAX = 20.0f;
constexpr float PHI_MIN = 8.5e-8f;
constexpr float PHI_MAX = 16.635532f;

// ---- full-accuracy reference primitives (table init + fallback path) ----
__device__ __forceinline__ double lean_exp(double x) {
    double t = x * 1.4426950408889634;
    double k = __builtin_rint(t);
    double r = __builtin_fma(-k, 0.6931471805599453, x);
    r = __builtin_fma(-k, 2.3190468138462996e-17, r);
    double p = 1.0 / 3628800.0;                  // Taylor deg 10, |r|<=0.347
    p = __builtin_fma(p, r, 1.0 / 362880.0);
    p = __builtin_fma(p, r, 1.0 / 40320.0);
    p = __builtin_fma(p, r, 1.0 / 5040.0);
    p = __builtin_fma(p, r, 1.0 / 720.0);
    p = __builtin_fma(p, r, 1.0 / 120.0);
    p = __builtin_fma(p, r, 1.0 / 24.0);
    p = __builtin_fma(p, r, 1.0 / 6.0);
    p = __builtin_fma(p, r, 0.5);
    p = __builtin_fma(p, r, 1.0);
    p = __builtin_fma(p, r, 1.0);
    int ik = (int)k;                              // k in [0,24]
    double s = __hiloint2double((1023 + ik) << 20, 0);
    return p * s;
}

__device__ __forceinline__ double lean_log(double v) {
    int hv = __double2hiint(v);
    int lv = __double2loint(v);
    int e  = (hv >> 20) - 1023;
    double m = __hiloint2double((hv & 0x000FFFFF) | 0x3FF00000, lv);
    if (m >= 1.4142135623730951) { m *= 0.5; e += 1; }   // m in [0.7071,1.4142)
    double t = m - 1.0;
    double d = t + 2.0;
    double r = (double)__builtin_amdgcn_rcpf((float)d);
    r = __builtin_fma(__builtin_fma(-d, r, 1.0), r, r);
    double u = t * r;
    double w = u * u;
    double P = 2.0 / 13.0;                        // 2*artanh: deg 6 in w
    P = __builtin_fma(P, w, 2.0 / 11.0);
    P = __builtin_fma(P, w, 2.0 / 9.0);
    P = __builtin_fma(P, w, 2.0 / 7.0);
    P = __builtin_fma(P, w, 2.0 / 5.0);
    P = __builtin_fma(P, w, 2.0 / 3.0);
    P = __builtin_fma(P, w, 2.0);
    double lm = u * P;
    return __builtin_fma((double)e, 0.6931471805599453, lm);
}

__device__ __forceinline__ float phi_f(float xf) {
    xf = fminf(fmaxf(xf, PHI_MIN), PHI_MAX);
    float exf = (float)lean_exp((double)xf);
    float af = exf + 1.0f;
    float bf = exf - 1.0f;
    float la = (float)lean_log((double)af);
    float lb = (float)lean_log((double)bf);
    return la - lb;
}

// ---- fast table primitives (main path) ----
constexpr double EXP_STEP = 0.021660849392498291;   // double(ln2/32)
constexpr double EXP_INV  = 46.166241308446828;     // 32/ln2

// e^x, x in [0, 16.64]; rel err <= r^4/24 ~ 2^-30.7, and -> 0 as x -> 0.
__device__ __forceinline__ double fast_exp(double x, const double* et) {
    double kd = __builtin_rint(x * EXP_INV);
    double r  = __builtin_fma(-kd, EXP_STEP, x);     // |r| <= 0.01083
    int n = (int)kd;                                 // [0, 768]
    double p = __builtin_fma(
        r, __builtin_fma(r, __builtin_fma(r, 1.0 / 6.0, 0.5), 1.0), 1.0);
    double s = et[n & 31];                           // 2^(j/32)
    int sh = __double2hiint(s) + ((n >> 5) << 20);   // * 2^k
    s = __hiloint2double(sh, __double2loint(s));
    return p * s;
}

// log(v), v an exact f32 in [2^-23, 2^25]; abs err ~2^-34.
// 256-entry table, entry = double2{1/t, log t}; log1p poly deg-3.
__device__ __forceinline__ double fast_log(double v, const double2* lt) {
    int hv = __double2hiint(v);
    int lv = __double2loint(v);
    int E  = (hv >> 20) - 1023;
    double m = __hiloint2double((hv & 0x000FFFFF) | 0x3FF00000, lv); // [1,2)
    int idx = (hv >> 12) & 255;
    double2 te = lt[idx];                            // {1/t, log t}
    double t = __hiloint2double(0x3FF00000 | (idx << 12), 0);        // 1+idx/256
    double d = m - t;                                // exact (Sterbenz)
    double f = d * te.x;                             // d / t, f in [0, 2^-8)
    double P = __builtin_fma(f, 1.0 / 3.0, -0.5);
    double q = __builtin_fma(f * f, P, f);           // log1p(f), deg 3
    return __builtin_fma((double)E, 0.6931471805599453, te.y + q);
}

// literal reference chain with table primitives (same f32 rounding points).
__device__ __forceinline__ float phi_fast(float xf, const double2* lt,
                                          const double* et) {
    xf = fminf(fmaxf(xf, PHI_MIN), PHI_MAX);
    float exf = (float)fast_exp((double)xf, et);
    float af = exf + 1.0f;
    float bf = exf - 1.0f;
    float la = (float)fast_log((double)af, lt);
    float lb = (float)fast_log((double)bf, lt);
    return la - lb;
}

// ---- fused CN kernel, XCD-sharded: one thread per (b, c). ----
template<int FIRST>
__global__ __launch_bounds__(256)
void cn_fused(const float* __restrict__ llr, const float* __restrict__ msgIn,
              float* __restrict__ msgOut)
{
    __shared__ double2 lt[256];  // {1/t, log t} per 256 mantissa bins (4 KB)
    __shared__ double  et[32];   // 2^(j/32)
    {
        int tid = threadIdx.x;
        {
            double t = 1.0 + tid * 0.00390625;       // 1 + idx/256
            double r0 = (double)__builtin_amdgcn_rcpf((float)t);
            r0 = __builtin_fma(__builtin_fma(-t, r0, 1.0), r0, r0);
            r0 = __builtin_fma(__builtin_fma(-t, r0, 1.0), r0, r0);
            lt[tid] = make_double2(r0, lean_log(t));
        }
        if (tid < 32) et[tid] = lean_exp(tid * EXP_STEP);
    }
    __syncthreads();

    int bid = blockIdx.x;
    int seq = bid >> 3;                          // [0, 512)
    int b   = (bid & 7) * 16 + (seq >> 5);       // 16 batches per XCD
    int c   = (seq & 31) * 256 + threadIdx.x;    // [0, 8192)

    const float* mi = msgIn + (size_t)b * NUM_EDGES;
    float* mo = msgOut + (size_t)b * NUM_EDGES;
    const float* lbp = llr + (size_t)b * NUM_VNS;

    float g[6];                                     // signed mags (sign in bit)
#pragma unroll
    for (int t = 0; t < 6; ++t) {
        int e = c + (t << 13);
        int v = (int)(((unsigned)e * 43691u) >> 17);  // e/3, e < 98304
        float x = fminf(fmaxf(lbp[v], -LLR_MAX), LLR_MAX);
        float m;
        if (FIRST) {
            m = -x;                                   // msgs are all zero
        } else {
            int e0 = 3 * v;
            int j  = e - e0;                          // e mod 3
            float m0 = mi[e0], m1 = mi[e0 + 1], m2 = mi[e0 + 2];
            float s = ((m0 + m1) + m2) - x;           // exact reference order
            float own = (j == 0) ? m0 : ((j == 1) ? m1 : m2);
            m = s - own;                              // vn-extrinsic
        }
        unsigned neg = (m < 0.0f) ? 0x80000000u : 0u; // sign(0) -> +1
        float mg = phi_fast(fabsf(m), lt, et);
        g[t] = __uint_as_float(__float_as_uint(mg) | neg);
    }
    float a0 = fabsf(g[0]), a1 = fabsf(g[1]), a2 = fabsf(g[2]);
    float a3 = fabsf(g[3]), a4 = fabsf(g[4]), a5 = fabsf(g[5]);
    float ms = ((((a0 + a1) + a2) + a3) + a4) + a5;   // reference left-fold
    unsigned all6 = (__float_as_uint(g[0]) ^ __float_as_uint(g[1])
                   ^ __float_as_uint(g[2]) ^ __float_as_uint(g[3])
                   ^ __float_as_uint(g[4]) ^ __float_as_uint(g[5]))
                  & 0x80000000u;
#pragma unroll
    for (int t = 0; t < 6; ++t) {
        int e = c + (t << 13);
        float o = phi_fast(ms - fabsf(g[t]), lt, et);
        unsigned sg = all6 ^ (__float_as_uint(g[t]) & 0x80000000u);
        mo[e] = __uint_as_float(__float_as_uint(o) ^ sg);
    }
}

// ---- final marginalize, XCD-sharded to match cn_fused's batch->XCD map. ----
__global__ __launch_bounds__(256)
void vn_final(const float* __restrict__ llr, const float* __restrict__ msg,
              float* __restrict__ outv)
{
    int bid = blockIdx.x;                        // 8192 blocks
    int seq = bid >> 3;                          // [0, 1024)
    int b   = (bid & 7) * 16 + (seq >> 6);       // 16 batches per XCD
    int v   = (seq & 63) * 256 + threadIdx.x;    // [0, 16384)
    float x = fminf(fmaxf(llr[(size_t)b * NUM_VNS + v], -LLR_MAX), LLR_MAX);
    const float* mb = msg + (size_t)b * NUM_EDGES;
    int e = 3 * v;
    float s = ((mb[e] + mb[e + 1]) + mb[e + 2]) - x;  // exact reference order
    outv[(size_t)b * NUM_VNS + v] = -s;
}

// ---- VN kernel (r12 fallback). ----
template<int FIRST, int LAST>
__global__ __launch_bounds__(256)
void vn_kernel(const float* __restrict__ llr, const float* __restrict__ msg,
               float* __restrict__ outv)
{
    int gid = blockIdx.x * 256 + threadIdx.x;       // b*16384 + v
    int b = gid >> 14;
    int v = gid & 16383;
    float x = fminf(fmaxf(llr[gid], -LLR_MAX), LLR_MAX);
    float s;
    if (FIRST) {
        s = -x;
    } else {
        const float* mb = msg + (size_t)b * NUM_EDGES;
        int e = 3 * v;
        s = ((mb[e] + mb[e + 1]) + mb[e + 2]) - x;
    }
    outv[gid] = LAST ? -s : s;
}

// ---- CN kernel (r12 fallback, reads precomputed vtot). ----
template<int FIRST>
__global__ __launch_bounds__(256)
void cn_kernel(float* __restrict__ msg, const float* __restrict__ vtot)
{
    int gid = blockIdx.x * 256 + threadIdx.x;       // b*8192 + c
    int b = gid >> 13;
    int c = gid & 8191;
    float* mb = msg + (size_t)b * NUM_EDGES;
    const float* vt = vtot + (size_t)b * NUM_VNS;

    float g[6];
#pragma unroll
    for (int t = 0; t < 6; ++t) {
        int e = c + (t << 13);
        int v = (int)(((unsigned)e * 43691u) >> 17);
        float m = FIRST ? vt[v] : (vt[v] - mb[e]);
        unsigned neg = (m < 0.0f) ? 0x80000000u : 0u;
        float mg = phi_f(fabsf(m));
        g[t] = __uint_as_float(__float_as_uint(mg) | neg);
    }
    float a0 = fabsf(g[0]), a1 = fabsf(g[1]), a2 = fabsf(g[2]);
    float a3 = fabsf(g[3]), a4 = fabsf(g[4]), a5 = fabsf(g[5]);
    float ms = ((((a0 + a1) + a2) + a3) + a4) + a5;
    unsigned all6 = (__float_as_uint(g[0]) ^ __float_as_uint(g[1])
                   ^ __float_as_uint(g[2]) ^ __float_as_uint(g[3])
                   ^ __float_as_uint(g[4]) ^ __float_as_uint(g[5]))
                  & 0x80000000u;
#pragma unroll
    for (int t = 0; t < 6; ++t) {
        int e = c + (t << 13);
        float o = phi_f(ms - fabsf(g[t]));
        unsigned sg = all6 ^ (__float_as_uint(g[t]) & 0x80000000u);
        mb[e] = __uint_as_float(__float_as_uint(o) ^ sg);
    }
}

extern "C" void kernel_launch(void* const* d_in, const int* in_sizes, int n_in,
                              void* d_out, int out_size, void* d_ws, size_t ws_size,
                              hipStream_t stream) {
    const float* llr = (const float*)d_in[0];
    float* out = (float*)d_out;

    const int VNB = BATCH * NUM_VNS / 256;             // 8192 blocks
    const int CNB = BATCH * NUM_CNS / 256;             // 4096 blocks
    const size_t MSGSZ = (size_t)BATCH * NUM_EDGES;    // 6.29M floats = 24 MB

    if (ws_size >= 2 * MSGSZ * sizeof(float)) {
        // ---- fused path: 8 CN launches (double-buffered) + final VN ----
        float* buf0 = (float*)d_ws;
        float* buf1 = buf0 + MSGSZ;
        cn_fused<1><<<CNB, 256, 0, stream>>>(llr, buf0, buf0);     // writes buf0
        for (int it = 1; it < NUM_ITER; ++it) {
            float* in  = (it & 1) ? buf0 : buf1;
            float* dst = (it & 1) ? buf1 : buf0;
            cn_fused<0><<<CNB, 256, 0, stream>>>(llr, in, dst);
        }
        // NUM_ITER=8: last write was buf1 (it=7 -> dst=buf1)
        vn_final<<<VNB, 256, 0, stream>>>(llr, buf1, out);
    } else {
        // ---- r12 fallback: 32 MB workspace ----
        float* msg  = (float*)d_ws;
        float* vtot = msg + MSGSZ;
        vn_kernel<1, 0><<<VNB, 256, 0, stream>>>(llr, msg, vtot);
        cn_kernel<1><<<CNB, 256, 0, stream>>>(msg, vtot);
        for (int it = 1; it < NUM_ITER; ++it) {
            vn_kernel<0, 0><<<VNB, 256, 0, stream>>>(llr, msg, vtot);
            cn_kernel<0><<<CNB, 256, 0, stream>>>(msg, vtot);
        }
        vn_kernel<0, 1><<<VNB, 256, 0, stream>>>(llr, msg, out);
    }
}

// Round 20
// 203.820 us; speedup vs baseline: 1.0672x; 1.0035x over previous
//
#include <hip/hip_runtime.h>

// LDPC BP decoder, (3,6)-regular — fused full-chip version, table-phi v4.
// Edge e (vn order) = 3v+j; c = e mod 8192, t = e div 8192, e = c + 8192t.
//
// r19 post-mortem: hw __logf (dense ~2ulp) failed at 10.0, mirroring r10's
// hw exp failure. Locked constraint: ALL phi intermediates need >=~7 guard
// bits beyond f32 (rare ~1% 1-ulp flips OK; dense deviations amplified
// ~2.5e6x by loopy-BP chaos). r20 = r18 (known-good, 204.5us) + one
// accuracy-IMPROVING shave: exp table 32->256 entries, poly deg-3 -> deg-2
// (rel err 2^-31.2 < r18's 2^-30.9; error still -> 0 as x -> 0, protecting
// the b = ex-1 quantization channel).

constexpr int NUM_VNS   = 16384;
constexpr int NUM_CNS   = 8192;
constexpr int NUM_EDGES = 49152;
constexpr int BATCH     = 128;
constexpr int NUM_ITER  = 8;
constexpr float LLR_MAX = 20.0f;
constexpr float PHI_MIN = 8.5e-8f;
constexpr float PHI_MAX = 16.635532f;

// ---- full-accuracy reference primitives (table init + fallback path) ----
__device__ __forceinline__ double lean_exp(double x) {
    double t = x * 1.4426950408889634;
    double k = __builtin_rint(t);
    double r = __builtin_fma(-k, 0.6931471805599453, x);
    r = __builtin_fma(-k, 2.3190468138462996e-17, r);
    double p = 1.0 / 3628800.0;                  // Taylor deg 10, |r|<=0.347
    p = __builtin_fma(p, r, 1.0 / 362880.0);
    p = __builtin_fma(p, r, 1.0 / 40320.0);
    p = __builtin_fma(p, r, 1.0 / 5040.0);
    p = __builtin_fma(p, r, 1.0 / 720.0);
    p = __builtin_fma(p, r, 1.0 / 120.0);
    p = __builtin_fma(p, r, 1.0 / 24.0);
    p = __builtin_fma(p, r, 1.0 / 6.0);
    p = __builtin_fma(p, r, 0.5);
    p = __builtin_fma(p, r, 1.0);
    p = __builtin_fma(p, r, 1.0);
    int ik = (int)k;                              // k in [0,24]
    double s = __hiloint2double((1023 + ik) << 20, 0);
    return p * s;
}

__device__ __forceinline__ double lean_log(double v) {
    int hv = __double2hiint(v);
    int lv = __double2loint(v);
    int e  = (hv >> 20) - 1023;
    double m = __hiloint2double((hv & 0x000FFFFF) | 0x3FF00000, lv);
    if (m >= 1.4142135623730951) { m *= 0.5; e += 1; }   // m in [0.7071,1.4142)
    double t = m - 1.0;
    double d = t + 2.0;
    double r = (double)__builtin_amdgcn_rcpf((float)d);
    r = __builtin_fma(__builtin_fma(-d, r, 1.0), r, r);
    double u = t * r;
    double w = u * u;
    double P = 2.0 / 13.0;                        // 2*artanh: deg 6 in w
    P = __builtin_fma(P, w, 2.0 / 11.0);
    P = __builtin_fma(P, w, 2.0 / 9.0);
    P = __builtin_fma(P, w, 2.0 / 7.0);
    P = __builtin_fma(P, w, 2.0 / 5.0);
    P = __builtin_fma(P, w, 2.0 / 3.0);
    P = __builtin_fma(P, w, 2.0);
    double lm = u * P;
    return __builtin_fma((double)e, 0.6931471805599453, lm);
}

__device__ __forceinline__ float phi_f(float xf) {
    xf = fminf(fmaxf(xf, PHI_MIN), PHI_MAX);
    float exf = (float)lean_exp((double)xf);
    float af = exf + 1.0f;
    float bf = exf - 1.0f;
    float la = (float)lean_log((double)af);
    float lb = (float)lean_log((double)bf);
    return la - lb;
}

// ---- fast table primitives (main path) ----
constexpr double EXP_STEP = 0.0027076061740622864;  // double(ln2/256)
constexpr double EXP_INV  = 369.32993046757465;     // 256/ln2

// e^x, x in [0, 16.64]; rel err <= r^3/6 ~ 2^-31.2, and -> 0 as x -> 0.
__device__ __forceinline__ double fast_exp(double x, const double* et) {
    double kd = __builtin_rint(x * EXP_INV);
    double r  = __builtin_fma(-kd, EXP_STEP, x);     // |r| <= 0.001354
    int n = (int)kd;                                 // [0, 6145]
    double p = __builtin_fma(r, __builtin_fma(r, 0.5, 1.0), 1.0);  // deg 2
    double s = et[n & 255];                          // 2^(j/256)
    int sh = __double2hiint(s) + ((n >> 8) << 20);   // * 2^k
    s = __hiloint2double(sh, __double2loint(s));
    return p * s;
}

// log(v), v an exact f32 in [2^-23, 2^25]; abs err ~2^-34.
// 256-entry table, entry = double2{1/t, log t}; log1p poly deg-3.
__device__ __forceinline__ double fast_log(double v, const double2* lt) {
    int hv = __double2hiint(v);
    int lv = __double2loint(v);
    int E  = (hv >> 20) - 1023;
    double m = __hiloint2double((hv & 0x000FFFFF) | 0x3FF00000, lv); // [1,2)
    int idx = (hv >> 12) & 255;
    double2 te = lt[idx];                            // {1/t, log t}
    double t = __hiloint2double(0x3FF00000 | (idx << 12), 0);        // 1+idx/256
    double d = m - t;                                // exact (Sterbenz)
    double f = d * te.x;                             // d / t, f in [0, 2^-8)
    double P = __builtin_fma(f, 1.0 / 3.0, -0.5);
    double q = __builtin_fma(f * f, P, f);           // log1p(f), deg 3
    return __builtin_fma((double)E, 0.6931471805599453, te.y + q);
}

// literal reference chain with table primitives (same f32 rounding points).
__device__ __forceinline__ float phi_fast(float xf, const double2* lt,
                                          const double* et) {
    xf = fminf(fmaxf(xf, PHI_MIN), PHI_MAX);
    float exf = (float)fast_exp((double)xf, et);
    float af = exf + 1.0f;
    float bf = exf - 1.0f;
    float la = (float)fast_log((double)af, lt);
    float lb = (float)fast_log((double)bf, lt);
    return la - lb;
}

// ---- fused CN kernel, XCD-sharded: one thread per (b, c). ----
template<int FIRST>
__global__ __launch_bounds__(256)
void cn_fused(const float* __restrict__ llr, const float* __restrict__ msgIn,
              float* __restrict__ msgOut)
{
    __shared__ double2 lt[256];  // {1/t, log t} per 256 mantissa bins (4 KB)
    __shared__ double  et[256];  // 2^(j/256)                        (2 KB)
    {
        int tid = threadIdx.x;
        {
            double t = 1.0 + tid * 0.00390625;       // 1 + idx/256
            double r0 = (double)__builtin_amdgcn_rcpf((float)t);
            r0 = __builtin_fma(__builtin_fma(-t, r0, 1.0), r0, r0);
            r0 = __builtin_fma(__builtin_fma(-t, r0, 1.0), r0, r0);
            lt[tid] = make_double2(r0, lean_log(t));
        }
        et[tid] = lean_exp(tid * EXP_STEP);
    }
    __syncthreads();

    int bid = blockIdx.x;
    int seq = bid >> 3;                          // [0, 512)
    int b   = (bid & 7) * 16 + (seq >> 5);       // 16 batches per XCD
    int c   = (seq & 31) * 256 + threadIdx.x;    // [0, 8192)

    const float* mi = msgIn + (size_t)b * NUM_EDGES;
    float* mo = msgOut + (size_t)b * NUM_EDGES;
    const float* lbp = llr + (size_t)b * NUM_VNS;

    float g[6];                                     // signed mags (sign in bit)
#pragma unroll
    for (int t = 0; t < 6; ++t) {
        int e = c + (t << 13);
        int v = (int)(((unsigned)e * 43691u) >> 17);  // e/3, e < 98304
        float x = fminf(fmaxf(lbp[v], -LLR_MAX), LLR_MAX);
        float m;
        if (FIRST) {
            m = -x;                                   // msgs are all zero
        } else {
            int e0 = 3 * v;
            int j  = e - e0;                          // e mod 3
            float m0 = mi[e0], m1 = mi[e0 + 1], m2 = mi[e0 + 2];
            float s = ((m0 + m1) + m2) - x;           // exact reference order
            float own = (j == 0) ? m0 : ((j == 1) ? m1 : m2);
            m = s - own;                              // vn-extrinsic
        }
        unsigned neg = (m < 0.0f) ? 0x80000000u : 0u; // sign(0) -> +1
        float mg = phi_fast(fabsf(m), lt, et);
        g[t] = __uint_as_float(__float_as_uint(mg) | neg);
    }
    float a0 = fabsf(g[0]), a1 = fabsf(g[1]), a2 = fabsf(g[2]);
    float a3 = fabsf(g[3]), a4 = fabsf(g[4]), a5 = fabsf(g[5]);
    float ms = ((((a0 + a1) + a2) + a3) + a4) + a5;   // reference left-fold
    unsigned all6 = (__float_as_uint(g[0]) ^ __float_as_uint(g[1])
                   ^ __float_as_uint(g[2]) ^ __float_as_uint(g[3])
                   ^ __float_as_uint(g[4]) ^ __float_as_uint(g[5]))
                  & 0x80000000u;
#pragma unroll
    for (int t = 0; t < 6; ++t) {
        int e = c + (t << 13);
        float o = phi_fast(ms - fabsf(g[t]), lt, et);
        unsigned sg = all6 ^ (__float_as_uint(g[t]) & 0x80000000u);
        mo[e] = __uint_as_float(__float_as_uint(o) ^ sg);
    }
}

// ---- final marginalize, XCD-sharded to match cn_fused's batch->XCD map. ----
__global__ __launch_bounds__(256)
void vn_final(const float* __restrict__ llr, const float* __restrict__ msg,
              float* __restrict__ outv)
{
    int bid = blockIdx.x;                        // 8192 blocks
    int seq = bid >> 3;                          // [0, 1024)
    int b   = (bid & 7) * 16 + (seq >> 6);       // 16 batches per XCD
    int v   = (seq & 63) * 256 + threadIdx.x;    // [0, 16384)
    float x = fminf(fmaxf(llr[(size_t)b * NUM_VNS + v], -LLR_MAX), LLR_MAX);
    const float* mb = msg + (size_t)b * NUM_EDGES;
    int e = 3 * v;
    float s = ((mb[e] + mb[e + 1]) + mb[e + 2]) - x;  // exact reference order
    outv[(size_t)b * NUM_VNS + v] = -s;
}

// ---- VN kernel (r12 fallback). ----
template<int FIRST, int LAST>
__global__ __launch_bounds__(256)
void vn_kernel(const float* __restrict__ llr, const float* __restrict__ msg,
               float* __restrict__ outv)
{
    int gid = blockIdx.x * 256 + threadIdx.x;       // b*16384 + v
    int b = gid >> 14;
    int v = gid & 16383;
    float x = fminf(fmaxf(llr[gid], -LLR_MAX), LLR_MAX);
    float s;
    if (FIRST) {
        s = -x;
    } else {
        const float* mb = msg + (size_t)b * NUM_EDGES;
        int e = 3 * v;
        s = ((mb[e] + mb[e + 1]) + mb[e + 2]) - x;
    }
    outv[gid] = LAST ? -s : s;
}

// ---- CN kernel (r12 fallback, reads precomputed vtot). ----
template<int FIRST>
__global__ __launch_bounds__(256)
void cn_kernel(float* __restrict__ msg, const float* __restrict__ vtot)
{
    int gid = blockIdx.x * 256 + threadIdx.x;       // b*8192 + c
    int b = gid >> 13;
    int c = gid & 8191;
    float* mb = msg + (size_t)b * NUM_EDGES;
    const float* vt = vtot + (size_t)b * NUM_VNS;

    float g[6];
#pragma unroll
    for (int t = 0; t < 6; ++t) {
        int e = c + (t << 13);
        int v = (int)(((unsigned)e * 43691u) >> 17);
        float m = FIRST ? vt[v] : (vt[v] - mb[e]);
        unsigned neg = (m < 0.0f) ? 0x80000000u : 0u;
        float mg = phi_f(fabsf(m));
        g[t] = __uint_as_float(__float_as_uint(mg) | neg);
    }
    float a0 = fabsf(g[0]), a1 = fabsf(g[1]), a2 = fabsf(g[2]);
    float a3 = fabsf(g[3]), a4 = fabsf(g[4]), a5 = fabsf(g[5]);
    float ms = ((((a0 + a1) + a2) + a3) + a4) + a5;
    unsigned all6 = (__float_as_uint(g[0]) ^ __float_as_uint(g[1])
                   ^ __float_as_uint(g[2]) ^ __float_as_uint(g[3])
                   ^ __float_as_uint(g[4]) ^ __float_as_uint(g[5]))
                  & 0x80000000u;
#pragma unroll
    for (int t = 0; t < 6; ++t) {
        int e = c + (t << 13);
        float o = phi_f(ms - fabsf(g[t]));
        unsigned sg = all6 ^ (__float_as_uint(g[t]) & 0x80000000u);
        mb[e] = __uint_as_float(__float_as_uint(o) ^ sg);
    }
}

extern "C" void kernel_launch(void* const* d_in, const int* in_sizes, int n_in,
                              void* d_out, int out_size, void* d_ws, size_t ws_size,
                              hipStream_t stream) {
    const float* llr = (const float*)d_in[0];
    float* out = (float*)d_out;

    const int VNB = BATCH * NUM_VNS / 256;             // 8192 blocks
    const int CNB = BATCH * NUM_CNS / 256;             // 4096 blocks
    const size_t MSGSZ = (size_t)BATCH * NUM_EDGES;    // 6.29M floats = 24 MB

    if (ws_size >= 2 * MSGSZ * sizeof(float)) {
        // ---- fused path: 8 CN launches (double-buffered) + final VN ----
        float* buf0 = (float*)d_ws;
        float* buf1 = buf0 + MSGSZ;
        cn_fused<1><<<CNB, 256, 0, stream>>>(llr, buf0, buf0);     // writes buf0
        for (int it = 1; it < NUM_ITER; ++it) {
            float* in  = (it & 1) ? buf0 : buf1;
            float* dst = (it & 1) ? buf1 : buf0;
            cn_fused<0><<<CNB, 256, 0, stream>>>(llr, in, dst);
        }
        // NUM_ITER=8: last write was buf1 (it=7 -> dst=buf1)
        vn_final<<<VNB, 256, 0, stream>>>(llr, buf1, out);
    } else {
        // ---- r12 fallback: 32 MB workspace ----
        float* msg  = (float*)d_ws;
        float* vtot = msg + MSGSZ;
        vn_kernel<1, 0><<<VNB, 256, 0, stream>>>(llr, msg, vtot);
        cn_kernel<1><<<CNB, 256, 0, stream>>>(msg, vtot);
        for (int it = 1; it < NUM_ITER; ++it) {
            vn_kernel<0, 0><<<VNB, 256, 0, stream>>>(llr, msg, vtot);
            cn_kernel<0><<<CNB, 256, 0, stream>>>(msg, vtot);
        }
        vn_kernel<0, 1><<<VNB, 256, 0, stream>>>(llr, msg, out);
    }
}